// Round 2
// baseline (261.082 us; speedup 1.0000x reference)
//
#include <hip/hip_runtime.h>
#include <hip/hip_bf16.h>
#include <stdint.h>

typedef short short8 __attribute__((ext_vector_type(8)));
typedef float f32x4 __attribute__((ext_vector_type(4)));

#define N_ATOMS 262144
#define NSYM 4
#define NIMG 1024

// ---------- bf16 round-to-nearest-even helpers ----------
__device__ __forceinline__ unsigned short rne_bf16(float f) {
  unsigned int u = __builtin_bit_cast(unsigned int, f);
  unsigned int r = u + 0x7fffu + ((u >> 16) & 1u);
  return (unsigned short)(r >> 16);
}
__device__ __forceinline__ float bf16f(unsigned short h) {
  unsigned int u = ((unsigned int)h) << 16;
  return __builtin_bit_cast(float, u);
}

// ---------- kernel 1: symbol histogram ----------
__global__ void hist_kernel(const int* __restrict__ sym, int* __restrict__ counts, int n) {
  int stride = gridDim.x * blockDim.x;
  int lane = threadIdx.x & 63;
  int c0 = 0, c1 = 0, c2 = 0, c3 = 0;
  for (int i = blockIdx.x * blockDim.x + threadIdx.x; i < n; i += stride) {
    int s = sym[i];
    c0 += (s == 0); c1 += (s == 1); c2 += (s == 2); c3 += (s == 3);
  }
  for (int m = 32; m; m >>= 1) {
    c0 += __shfl_down(c0, m); c1 += __shfl_down(c1, m);
    c2 += __shfl_down(c2, m); c3 += __shfl_down(c3, m);
  }
  if (lane == 0) {
    atomicAdd(&counts[0], c0); atomicAdd(&counts[1], c1);
    atomicAdd(&counts[2], c2); atomicAdd(&counts[3], c3);
  }
}

// ---------- kernel 2: padded offsets (groups aligned to 128) ----------
__global__ void offsets_kernel(const int* __restrict__ counts, int* __restrict__ offs,
                               int* __restrict__ cursors) {
  if (blockIdx.x == 0 && threadIdx.x == 0) {
    int o = 0;
    offs[0] = 0;
    for (int s = 0; s < NSYM; ++s) {
      cursors[s] = o;
      o += (counts[s] + 127) & ~127;
      offs[s + 1] = o;
    }
  }
}

// ---------- kernel 3: scatter atoms into symbol-grouped perm ----------
__global__ void scatter_kernel(const int* __restrict__ sym, int* __restrict__ cursors,
                               int* __restrict__ perm, int n) {
  int i = blockIdx.x * blockDim.x + threadIdx.x;
  int lane = threadIdx.x & 63;
  int wave = threadIdx.x >> 6;
  __shared__ int wcnt[4][NSYM];
  __shared__ int base[NSYM];
  int s = (i < n) ? sym[i] : -1;
  unsigned long long mymask = 0;
  for (int t = 0; t < NSYM; ++t) {
    unsigned long long m = __ballot(s == t);
    if (lane == 0) wcnt[wave][t] = __popcll(m);
    if (s == t) mymask = m;
  }
  __syncthreads();
  if (threadIdx.x < NSYM) {
    int t = threadIdx.x;
    int tot = wcnt[0][t] + wcnt[1][t] + wcnt[2][t] + wcnt[3][t];
    base[t] = atomicAdd(&cursors[t], tot);
  }
  __syncthreads();
  if (s >= 0) {
    int off = base[s];
    for (int w = 0; w < wave; ++w) off += wcnt[w][s];
    off += __popcll(mymask & ((1ull << lane) - 1ull));
    perm[off] = i;
  }
}

// ---------- kernel 4: weights -> transposed bf16 hi/lo tiles in ws ----------
// layout: wt[tile][h][d], tile = layer*4 + s (hi), 8 + layer*4 + s (lo)
__global__ void wconv_kernel(const float* __restrict__ W1, const float* __restrict__ W2,
                             unsigned short* __restrict__ wt) {
  int idx = blockIdx.x * blockDim.x + threadIdx.x;  // 0..131071
  int layer = idx >> 16;
  int rem = idx & 65535;
  int s = rem >> 14;
  int hd = rem & 16383;
  int h = hd >> 7, d = hd & 127;
  const float* W = layer ? W2 : W1;
  float v = W[(s * 128 + d) * 128 + h];
  unsigned short hi = rne_bf16(v);
  unsigned short lo = rne_bf16(v - bf16f(hi));
  int t = layer * 4 + s;
  wt[t * 16384 + h * 128 + d] = hi;
  wt[(8 + t) * 16384 + h * 128 + d] = lo;
}

// ---------- kernel 5: fused 2-layer MLP via MFMA ----------
__global__ __launch_bounds__(256) void mlp_gemm(
    const float* __restrict__ x, const unsigned short* __restrict__ wt,
    const int* __restrict__ perm, const int* __restrict__ offs,
    const float* __restrict__ b1, const float* __restrict__ b2,
    const float* __restrict__ W3, const float* __restrict__ b3,
    const float* __restrict__ slope, const float* __restrict__ intercept,
    float* __restrict__ e_atom) {
  extern __shared__ char lds[];
  char* XhB = lds;             // 32KB: X (later h1) hi
  char* XlB = lds + 32768;     // 32KB: X (later h1) lo
  char* WhB = lds + 65536;     // 32KB: W hi
  char* WlB = lds + 98304;     // 32KB: W lo

  int start = blockIdx.x * 128;
  if (start >= offs[4]) return;
  int s = 0;
  while (s < 3 && start >= offs[s + 1]) ++s;

  int tid = threadIdx.x;
  int wave = tid >> 6, lane = tid & 63;
  int halfw = lane >> 5, l32 = lane & 31;

  // ---- stage X tile (gathered rows, fp32 -> bf16 hi/lo, swizzled) ----
  for (int it = 0; it < 16; ++it) {
    int row = it * 8 + wave * 2 + halfw;
    int atom = perm[start + row];
    float4 v = make_float4(0.f, 0.f, 0.f, 0.f);
    if (atom >= 0) v = *(const float4*)(x + (long)atom * 128 + l32 * 4);
    ushort4 hp, lp;
    hp.x = rne_bf16(v.x); lp.x = rne_bf16(v.x - bf16f(hp.x));
    hp.y = rne_bf16(v.y); lp.y = rne_bf16(v.y - bf16f(hp.y));
    hp.z = rne_bf16(v.z); lp.z = rne_bf16(v.z - bf16f(hp.z));
    hp.w = rne_bf16(v.w); lp.w = rne_bf16(v.w - bf16f(hp.w));
    int off = row * 256 + ((l32 * 8) ^ ((row & 7) << 4));
    *(ushort4*)(XhB + off) = hp;
    *(ushort4*)(XlB + off) = lp;
  }
  // ---- stage W1t (already bf16 hi/lo in ws): 128 rows x 32 ushort4 chunks ----
  {
    const unsigned short* gh = wt + (size_t)(0 * 4 + s) * 16384;
    const unsigned short* gl = wt + (size_t)(8 + 0 * 4 + s) * 16384;
    for (int c = tid; c < 4096; c += 256) {
      int row = c >> 5;
      int cb = (c & 31) * 8;
      int off = row * 256 + (cb ^ ((row & 7) << 4));
      *(ushort4*)(WhB + off) = *(const ushort4*)(gh + row * 128 + (c & 31) * 4);
      *(ushort4*)(WlB + off) = *(const ushort4*)(gl + row * 128 + (c & 31) * 4);
    }
  }
  __syncthreads();

  // MFMA layer: C[128x128] += A[128x128] * B(=W^T stored [h][d])
  auto layer_mfma = [&](f32x4(&acc)[2][8]) {
#pragma unroll
    for (int k = 0; k < 4; ++k) {
      int kb = k * 64 + ((lane >> 4) * 16);  // byte offset of this lane's 8 k-elems
      short8 ah[2], al[2], bh[8], bl[8];
#pragma unroll
      for (int rf = 0; rf < 2; ++rf) {
        int row = wave * 32 + rf * 16 + (lane & 15);
        int off = row * 256 + (kb ^ ((row & 7) << 4));
        ah[rf] = *(const short8*)(XhB + off);
        al[rf] = *(const short8*)(XlB + off);
      }
#pragma unroll
      for (int cf = 0; cf < 8; ++cf) {
        int row = cf * 16 + (lane & 15);
        int off = row * 256 + (kb ^ ((row & 7) << 4));
        bh[cf] = *(const short8*)(WhB + off);
        bl[cf] = *(const short8*)(WlB + off);
      }
#pragma unroll
      for (int rf = 0; rf < 2; ++rf)
#pragma unroll
        for (int cf = 0; cf < 8; ++cf) {
          acc[rf][cf] = __builtin_amdgcn_mfma_f32_16x16x32_bf16(ah[rf], bh[cf], acc[rf][cf], 0, 0, 0);
          acc[rf][cf] = __builtin_amdgcn_mfma_f32_16x16x32_bf16(ah[rf], bl[cf], acc[rf][cf], 0, 0, 0);
          acc[rf][cf] = __builtin_amdgcn_mfma_f32_16x16x32_bf16(al[rf], bh[cf], acc[rf][cf], 0, 0, 0);
        }
    }
  };

  f32x4 zero4 = {0.f, 0.f, 0.f, 0.f};
  f32x4 acc[2][8];
#pragma unroll
  for (int i = 0; i < 2; ++i)
#pragma unroll
    for (int j = 0; j < 8; ++j) acc[i][j] = zero4;

  layer_mfma(acc);  // layer 1
  __syncthreads();  // all reads of X/W1 done

  // ---- epilogue 1: h1 = relu(acc + b1) -> hi/lo back into X buffers ----
#pragma unroll
  for (int rf = 0; rf < 2; ++rf)
#pragma unroll
    for (int cf = 0; cf < 8; ++cf) {
      int col = cf * 16 + (lane & 15);
      float bias = b1[s * 128 + col];
#pragma unroll
      for (int r = 0; r < 4; ++r) {
        int row = wave * 32 + rf * 16 + (lane >> 4) * 4 + r;
        float vv = fmaxf(acc[rf][cf][r] + bias, 0.f);
        unsigned short hi = rne_bf16(vv);
        unsigned short lo = rne_bf16(vv - bf16f(hi));
        int off = row * 256 + ((col * 2) ^ ((row & 7) << 4));
        *(unsigned short*)(XhB + off) = hi;
        *(unsigned short*)(XlB + off) = lo;
      }
    }
  // ---- stage W2t: 128 rows x 32 ushort4 chunks ----
  {
    const unsigned short* gh = wt + (size_t)(4 + s) * 16384;
    const unsigned short* gl = wt + (size_t)(8 + 4 + s) * 16384;
    for (int c = tid; c < 4096; c += 256) {
      int row = c >> 5;
      int cb = (c & 31) * 8;
      int off = row * 256 + (cb ^ ((row & 7) << 4));
      *(ushort4*)(WhB + off) = *(const ushort4*)(gh + row * 128 + (c & 31) * 4);
      *(ushort4*)(WlB + off) = *(const ushort4*)(gl + row * 128 + (c & 31) * 4);
    }
  }
  __syncthreads();

  f32x4 acc2[2][8];
#pragma unroll
  for (int i = 0; i < 2; ++i)
#pragma unroll
    for (int j = 0; j < 8; ++j) acc2[i][j] = zero4;

  layer_mfma(acc2);  // layer 2

  // ---- epilogue 2+3: e = relu(h2 + b2) . W3, then affine, scatter ----
  float p[2][4] = {{0.f, 0.f, 0.f, 0.f}, {0.f, 0.f, 0.f, 0.f}};
#pragma unroll
  for (int rf = 0; rf < 2; ++rf)
#pragma unroll
    for (int cf = 0; cf < 8; ++cf) {
      int col = cf * 16 + (lane & 15);
      float b2v = b2[s * 128 + col];
      float w3v = W3[s * 128 + col];
#pragma unroll
      for (int r = 0; r < 4; ++r) {
        float vv = fmaxf(acc2[rf][cf][r] + b2v, 0.f);
        p[rf][r] += vv * w3v;
      }
    }
#pragma unroll
  for (int m = 1; m < 16; m <<= 1)
#pragma unroll
    for (int rf = 0; rf < 2; ++rf)
#pragma unroll
      for (int r = 0; r < 4; ++r) p[rf][r] += __shfl_xor(p[rf][r], m);

  if ((lane & 15) == 0) {
    float sl = slope[s], ic = intercept[s], bb = b3[s];
#pragma unroll
    for (int rf = 0; rf < 2; ++rf)
#pragma unroll
      for (int r = 0; r < 4; ++r) {
        int row = wave * 32 + rf * 16 + (lane >> 4) * 4 + r;
        int atom = perm[start + row];
        if (atom >= 0) e_atom[atom] = sl * (p[rf][r] + bb) + ic;
      }
  }
}

// ---------- kernel 6: deterministic per-image segment sum ----------
__global__ void segsum_kernel(const float* __restrict__ e_atom, const int* __restrict__ img,
                              float* __restrict__ out, int n) {
  int b = blockIdx.x;
  int lo = 0, hi = n;
  while (lo < hi) { int m = (lo + hi) >> 1; if (img[m] < b) lo = m + 1; else hi = m; }
  int lo2 = lo, hi2 = n;
  while (lo2 < hi2) { int m = (lo2 + hi2) >> 1; if (img[m] < b + 1) lo2 = m + 1; else hi2 = m; }
  float sum = 0.f;
  for (int i = lo + threadIdx.x; i < lo2; i += blockDim.x) sum += e_atom[i];
  for (int m = 32; m; m >>= 1) sum += __shfl_down(sum, m);
  __shared__ float part[4];
  int lane = threadIdx.x & 63, wave = threadIdx.x >> 6;
  if (lane == 0) part[wave] = sum;
  __syncthreads();
  if (threadIdx.x == 0) out[b] = part[0] + part[1] + part[2] + part[3];
}

extern "C" void kernel_launch(void* const* d_in, const int* in_sizes, int n_in,
                              void* d_out, int out_size, void* d_ws, size_t ws_size,
                              hipStream_t stream) {
  const float* x         = (const float*)d_in[0];
  const float* W1        = (const float*)d_in[1];
  const float* b1        = (const float*)d_in[2];
  const float* W2        = (const float*)d_in[3];
  const float* b2        = (const float*)d_in[4];
  const float* W3        = (const float*)d_in[5];
  const float* b3        = (const float*)d_in[6];
  const float* slope     = (const float*)d_in[7];
  const float* intercept = (const float*)d_in[8];
  const int* sym         = (const int*)d_in[9];
  const int* img         = (const int*)d_in[10];

  char* ws = (char*)d_ws;
  int* counts   = (int*)ws;                       // 16 B
  int* cursors  = (int*)(ws + 16);                // 16 B
  int* offs     = (int*)(ws + 32);                // 20 B
  int* perm     = (int*)(ws + 64);                // (N+512)*4 = 1050624 B
  float* e_atom = (float*)(ws + 64 + 1050624);    // N*4 = 1048576 B
  unsigned short* wt = (unsigned short*)(ws + 64 + 1050624 + 1048576);  // 512 KB

  hipMemsetAsync(counts, 0, 16, stream);
  hipMemsetAsync(perm, 0xFF, (N_ATOMS + 512) * sizeof(int), stream);

  hist_kernel<<<256, 256, 0, stream>>>(sym, counts, N_ATOMS);
  offsets_kernel<<<1, 64, 0, stream>>>(counts, offs, cursors);
  scatter_kernel<<<N_ATOMS / 256, 256, 0, stream>>>(sym, cursors, perm, N_ATOMS);
  wconv_kernel<<<512, 256, 0, stream>>>(W1, W2, wt);
  mlp_gemm<<<2052, 256, 131072, stream>>>(x, wt, perm, offs, b1, b2, W3, b3,
                                          slope, intercept, e_atom);
  segsum_kernel<<<NIMG, 256, 0, stream>>>(e_atom, img, (float*)d_out, N_ATOMS);
}

// Round 3
// 253.096 us; speedup vs baseline: 1.0316x; 1.0316x over previous
//
#include <hip/hip_runtime.h>
#include <hip/hip_bf16.h>
#include <stdint.h>

typedef short short8 __attribute__((ext_vector_type(8)));
typedef float f32x4 __attribute__((ext_vector_type(4)));
typedef unsigned int uint32x4 __attribute__((ext_vector_type(4)));

#define N_ATOMS 262144
#define NSYM 4
#define NIMG 1024

// ---------- bf16 round-to-nearest-even helpers ----------
__device__ __forceinline__ unsigned short rne_bf16(float f) {
  unsigned int u = __builtin_bit_cast(unsigned int, f);
  unsigned int r = u + 0x7fffu + ((u >> 16) & 1u);
  return (unsigned short)(r >> 16);
}
__device__ __forceinline__ float bf16f(unsigned short h) {
  unsigned int u = ((unsigned int)h) << 16;
  return __builtin_bit_cast(float, u);
}

// ---------- kernel 1: symbol histogram ----------
__global__ void hist_kernel(const int* __restrict__ sym, int* __restrict__ counts, int n) {
  int stride = gridDim.x * blockDim.x;
  int lane = threadIdx.x & 63;
  int c0 = 0, c1 = 0, c2 = 0, c3 = 0;
  for (int i = blockIdx.x * blockDim.x + threadIdx.x; i < n; i += stride) {
    int s = sym[i];
    c0 += (s == 0); c1 += (s == 1); c2 += (s == 2); c3 += (s == 3);
  }
  for (int m = 32; m; m >>= 1) {
    c0 += __shfl_down(c0, m); c1 += __shfl_down(c1, m);
    c2 += __shfl_down(c2, m); c3 += __shfl_down(c3, m);
  }
  if (lane == 0) {
    atomicAdd(&counts[0], c0); atomicAdd(&counts[1], c1);
    atomicAdd(&counts[2], c2); atomicAdd(&counts[3], c3);
  }
}

// ---------- kernel 2: padded offsets (groups aligned to 128) ----------
__global__ void offsets_kernel(const int* __restrict__ counts, int* __restrict__ offs,
                               int* __restrict__ cursors) {
  if (blockIdx.x == 0 && threadIdx.x == 0) {
    int o = 0;
    offs[0] = 0;
    for (int s = 0; s < NSYM; ++s) {
      cursors[s] = o;
      o += (counts[s] + 127) & ~127;
      offs[s + 1] = o;
    }
  }
}

// ---------- kernel 3: scatter atoms into symbol-grouped perm ----------
__global__ void scatter_kernel(const int* __restrict__ sym, int* __restrict__ cursors,
                               int* __restrict__ perm, int n) {
  int i = blockIdx.x * blockDim.x + threadIdx.x;
  int lane = threadIdx.x & 63;
  int wave = threadIdx.x >> 6;
  __shared__ int wcnt[4][NSYM];
  __shared__ int base[NSYM];
  int s = (i < n) ? sym[i] : -1;
  unsigned long long mymask = 0;
  for (int t = 0; t < NSYM; ++t) {
    unsigned long long m = __ballot(s == t);
    if (lane == 0) wcnt[wave][t] = __popcll(m);
    if (s == t) mymask = m;
  }
  __syncthreads();
  if (threadIdx.x < NSYM) {
    int t = threadIdx.x;
    int tot = wcnt[0][t] + wcnt[1][t] + wcnt[2][t] + wcnt[3][t];
    base[t] = atomicAdd(&cursors[t], tot);
  }
  __syncthreads();
  if (s >= 0) {
    int off = base[s];
    for (int w = 0; w < wave; ++w) off += wcnt[w][s];
    off += __popcll(mymask & ((1ull << lane) - 1ull));
    perm[off] = i;
  }
}

// ---------- kernel 4: weights -> transposed bf16 hi/lo planes in ws ----------
// plane t (16384 ushorts each): t = layer*4 + s (hi), 8 + layer*4 + s (lo)
// plane layout [h_out][k] with k contiguous (B-fragment order for MFMA)
__global__ void wconv_kernel(const float* __restrict__ W1, const float* __restrict__ W2,
                             unsigned short* __restrict__ wt) {
  int idx = blockIdx.x * blockDim.x + threadIdx.x;  // 0..131071
  int layer = idx >> 16;
  int rem = idx & 65535;
  int s = rem >> 14;
  int hd = rem & 16383;
  int h = hd >> 7, d = hd & 127;
  const float* W = layer ? W2 : W1;
  float v = W[(s * 128 + d) * 128 + h];
  unsigned short hi = rne_bf16(v);
  unsigned short lo = rne_bf16(v - bf16f(hi));
  int t = layer * 4 + s;
  wt[t * 16384 + h * 128 + d] = hi;
  wt[(8 + t) * 16384 + h * 128 + d] = lo;
}

// ---------- kernel 5: fused 2-layer MLP via MFMA ----------
// Per block: 128 atoms, 4 independent waves x 32 atoms. No __syncthreads.
// A (x rows) from global with in-reg hi/lo split; B (weights) from global (L2-hot);
// only h1 lives in LDS (per-wave 16KB, packed (hi<<16)|lo u32, XOR-swizzled).
__global__ __launch_bounds__(256, 2) void mlp_gemm(
    const float* __restrict__ x, const unsigned short* __restrict__ wt,
    const int* __restrict__ perm, const int* __restrict__ offs,
    const float* __restrict__ b1, const float* __restrict__ b2,
    const float* __restrict__ W3, const float* __restrict__ b3,
    const float* __restrict__ slope, const float* __restrict__ intercept,
    float* __restrict__ e_atom) {
  extern __shared__ char lds[];  // 64 KB: 4 waves x 16 KB h1

  int start = blockIdx.x * 128;
  if (start >= offs[4]) return;
  int s = 0;
  while (s < 3 && start >= offs[s + 1]) ++s;

  int tid = threadIdx.x;
  int wave = tid >> 6, lane = tid & 63;
  int r0 = lane & 15;        // row-in-tile / col-in-tile selector
  int chunk = lane >> 4;     // k-chunk selector (0..3)
  char* hbase = lds + wave * 16384;

  const unsigned short* gh1 = wt + (size_t)(0 + s) * 16384;
  const unsigned short* gl1 = wt + (size_t)(8 + s) * 16384;
  const unsigned short* gh2 = wt + (size_t)(4 + s) * 16384;
  const unsigned short* gl2 = wt + (size_t)(12 + s) * 16384;

  // atoms for this wave's 32 rows (A-fragment rows)
  int a0 = perm[start + wave * 32 + r0];
  int a1 = perm[start + wave * 32 + 16 + r0];

  // preload per-column constants (col = cf*16 + r0)
  float b1v[8];
#pragma unroll
  for (int cf = 0; cf < 8; ++cf) b1v[cf] = b1[s * 128 + cf * 16 + r0];

  // ---- layer-1 A fragments direct from global x, split hi/lo in-register ----
  short8 ah[8], al[8];  // frag f = rf*4 + k
#pragma unroll
  for (int rf = 0; rf < 2; ++rf) {
    int atom = rf ? a1 : a0;
    const float* xr = x + (long)(atom < 0 ? 0 : atom) * 128;
#pragma unroll
    for (int k = 0; k < 4; ++k) {
      int f = rf * 4 + k;
      float4 v0 = make_float4(0.f, 0.f, 0.f, 0.f), v1 = v0;
      if (atom >= 0) {
        v0 = *(const float4*)(xr + k * 32 + chunk * 8);
        v1 = *(const float4*)(xr + k * 32 + chunk * 8 + 4);
      }
      float vv[8] = {v0.x, v0.y, v0.z, v0.w, v1.x, v1.y, v1.z, v1.w};
      unsigned int hw[4], lw[4];
#pragma unroll
      for (int j = 0; j < 4; ++j) {
        unsigned short h0 = rne_bf16(vv[2 * j]), h1 = rne_bf16(vv[2 * j + 1]);
        unsigned short l0 = rne_bf16(vv[2 * j] - bf16f(h0));
        unsigned short l1 = rne_bf16(vv[2 * j + 1] - bf16f(h1));
        hw[j] = (unsigned int)h0 | ((unsigned int)h1 << 16);
        lw[j] = (unsigned int)l0 | ((unsigned int)l1 << 16);
      }
      uint32x4 hq = {hw[0], hw[1], hw[2], hw[3]};
      uint32x4 lq = {lw[0], lw[1], lw[2], lw[3]};
      ah[f] = __builtin_bit_cast(short8, hq);
      al[f] = __builtin_bit_cast(short8, lq);
    }
  }

  // ---- layer 1: acc = X * W1 (3-product hi/lo) ----
  f32x4 zero4 = {0.f, 0.f, 0.f, 0.f};
  f32x4 acc[2][8];
#pragma unroll
  for (int i = 0; i < 2; ++i)
#pragma unroll
    for (int j = 0; j < 8; ++j) acc[i][j] = zero4;

#pragma unroll
  for (int cf = 0; cf < 8; ++cf) {
    int brow = (cf * 16 + r0) * 128 + chunk * 8;
    short8 bh[4], bl[4];
#pragma unroll
    for (int k = 0; k < 4; ++k) {
      bh[k] = *(const short8*)(gh1 + brow + k * 32);
      bl[k] = *(const short8*)(gl1 + brow + k * 32);
    }
#pragma unroll
    for (int k = 0; k < 4; ++k)
#pragma unroll
      for (int rf = 0; rf < 2; ++rf) {
        int f = rf * 4 + k;
        acc[rf][cf] = __builtin_amdgcn_mfma_f32_16x16x32_bf16(ah[f], bh[k], acc[rf][cf], 0, 0, 0);
        acc[rf][cf] = __builtin_amdgcn_mfma_f32_16x16x32_bf16(ah[f], bl[k], acc[rf][cf], 0, 0, 0);
        acc[rf][cf] = __builtin_amdgcn_mfma_f32_16x16x32_bf16(al[f], bh[k], acc[rf][cf], 0, 0, 0);
      }
  }

  // ---- epilogue 1: h1 = relu(acc+b1) -> packed (hi<<16)|lo into per-wave LDS ----
  // write: 4B words, XOR-swizzle bits 4-6 by row -> 2-way max (free)
#pragma unroll
  for (int rf = 0; rf < 2; ++rf)
#pragma unroll
    for (int cf = 0; cf < 8; ++cf) {
      int col4 = (cf * 16 + r0) * 4;
#pragma unroll
      for (int rr = 0; rr < 4; ++rr) {
        int r = rf * 16 + chunk * 4 + rr;
        float v = fmaxf(acc[rf][cf][rr] + b1v[cf], 0.f);
        unsigned short h = rne_bf16(v);
        unsigned short l = rne_bf16(v - bf16f(h));
        *(unsigned int*)(hbase + r * 512 + (col4 ^ ((r & 7) << 4))) =
            ((unsigned int)h << 16) | l;
      }
    }

  // ---- layer-2 A fragments from LDS (per-wave private; no barrier needed) ----
  short8 ah2[8], al2[8];
#pragma unroll
  for (int rf = 0; rf < 2; ++rf) {
    int r = rf * 16 + r0;
    int xr = (r & 7) << 4;
#pragma unroll
    for (int k = 0; k < 4; ++k) {
      int g = k * 128 + chunk * 32;
      uint32x4 wa = *(const uint32x4*)(hbase + r * 512 + ((g) ^ xr));
      uint32x4 wb = *(const uint32x4*)(hbase + r * 512 + ((g + 16) ^ xr));
      unsigned int h01 = (wa[0] >> 16) | (wa[1] & 0xffff0000u);
      unsigned int h23 = (wa[2] >> 16) | (wa[3] & 0xffff0000u);
      unsigned int h45 = (wb[0] >> 16) | (wb[1] & 0xffff0000u);
      unsigned int h67 = (wb[2] >> 16) | (wb[3] & 0xffff0000u);
      unsigned int l01 = (wa[0] & 0xffffu) | (wa[1] << 16);
      unsigned int l23 = (wa[2] & 0xffffu) | (wa[3] << 16);
      unsigned int l45 = (wb[0] & 0xffffu) | (wb[1] << 16);
      unsigned int l67 = (wb[2] & 0xffffu) | (wb[3] << 16);
      uint32x4 hq = {h01, h23, h45, h67};
      uint32x4 lq = {l01, l23, l45, l67};
      int f = rf * 4 + k;
      ah2[f] = __builtin_bit_cast(short8, hq);
      al2[f] = __builtin_bit_cast(short8, lq);
    }
  }

  // ---- layer 2: acc2 = h1 * W2 ----
  f32x4 acc2[2][8];
#pragma unroll
  for (int i = 0; i < 2; ++i)
#pragma unroll
    for (int j = 0; j < 8; ++j) acc2[i][j] = zero4;

#pragma unroll
  for (int cf = 0; cf < 8; ++cf) {
    int brow = (cf * 16 + r0) * 128 + chunk * 8;
    short8 bh[4], bl[4];
#pragma unroll
    for (int k = 0; k < 4; ++k) {
      bh[k] = *(const short8*)(gh2 + brow + k * 32);
      bl[k] = *(const short8*)(gl2 + brow + k * 32);
    }
#pragma unroll
    for (int k = 0; k < 4; ++k)
#pragma unroll
      for (int rf = 0; rf < 2; ++rf) {
        int f = rf * 4 + k;
        acc2[rf][cf] = __builtin_amdgcn_mfma_f32_16x16x32_bf16(ah2[f], bh[k], acc2[rf][cf], 0, 0, 0);
        acc2[rf][cf] = __builtin_amdgcn_mfma_f32_16x16x32_bf16(ah2[f], bl[k], acc2[rf][cf], 0, 0, 0);
        acc2[rf][cf] = __builtin_amdgcn_mfma_f32_16x16x32_bf16(al2[f], bh[k], acc2[rf][cf], 0, 0, 0);
      }
  }

  // ---- epilogue 2: e = relu(acc2+b2).W3, affine, scatter ----
  float p[2][4] = {{0.f, 0.f, 0.f, 0.f}, {0.f, 0.f, 0.f, 0.f}};
#pragma unroll
  for (int cf = 0; cf < 8; ++cf) {
    int col = cf * 16 + r0;
    float b2v = b2[s * 128 + col];
    float w3v = W3[s * 128 + col];
#pragma unroll
    for (int rf = 0; rf < 2; ++rf)
#pragma unroll
      for (int rr = 0; rr < 4; ++rr)
        p[rf][rr] += fmaxf(acc2[rf][cf][rr] + b2v, 0.f) * w3v;
  }
#pragma unroll
  for (int m = 1; m < 16; m <<= 1)
#pragma unroll
    for (int rf = 0; rf < 2; ++rf)
#pragma unroll
      for (int rr = 0; rr < 4; ++rr) p[rf][rr] += __shfl_xor(p[rf][rr], m);

  if (r0 == 0) {
    float sl = slope[s], ic = intercept[s], bb = b3[s];
#pragma unroll
    for (int rf = 0; rf < 2; ++rf)
#pragma unroll
      for (int rr = 0; rr < 4; ++rr) {
        int row = wave * 32 + rf * 16 + chunk * 4 + rr;
        int atom = perm[start + row];
        if (atom >= 0) e_atom[atom] = sl * (p[rf][rr] + bb) + ic;
      }
  }
}

// ---------- kernel 6: deterministic per-image segment sum ----------
__global__ void segsum_kernel(const float* __restrict__ e_atom, const int* __restrict__ img,
                              float* __restrict__ out, int n) {
  int b = blockIdx.x;
  int lo = 0, hi = n;
  while (lo < hi) { int m = (lo + hi) >> 1; if (img[m] < b) lo = m + 1; else hi = m; }
  int lo2 = lo, hi2 = n;
  while (lo2 < hi2) { int m = (lo2 + hi2) >> 1; if (img[m] < b + 1) lo2 = m + 1; else hi2 = m; }
  float sum = 0.f;
  for (int i = lo + threadIdx.x; i < lo2; i += blockDim.x) sum += e_atom[i];
  for (int m = 32; m; m >>= 1) sum += __shfl_down(sum, m);
  __shared__ float part[4];
  int lane = threadIdx.x & 63, wave = threadIdx.x >> 6;
  if (lane == 0) part[wave] = sum;
  __syncthreads();
  if (threadIdx.x == 0) out[b] = part[0] + part[1] + part[2] + part[3];
}

extern "C" void kernel_launch(void* const* d_in, const int* in_sizes, int n_in,
                              void* d_out, int out_size, void* d_ws, size_t ws_size,
                              hipStream_t stream) {
  const float* x         = (const float*)d_in[0];
  const float* W1        = (const float*)d_in[1];
  const float* b1        = (const float*)d_in[2];
  const float* W2        = (const float*)d_in[3];
  const float* b2        = (const float*)d_in[4];
  const float* W3        = (const float*)d_in[5];
  const float* b3        = (const float*)d_in[6];
  const float* slope     = (const float*)d_in[7];
  const float* intercept = (const float*)d_in[8];
  const int* sym         = (const int*)d_in[9];
  const int* img         = (const int*)d_in[10];

  char* ws = (char*)d_ws;
  int* counts   = (int*)ws;                       // 16 B
  int* cursors  = (int*)(ws + 16);                // 16 B
  int* offs     = (int*)(ws + 32);                // 20 B
  int* perm     = (int*)(ws + 64);                // (N+512)*4
  float* e_atom = (float*)(ws + 64 + 1050624);    // N*4
  unsigned short* wt = (unsigned short*)(ws + 64 + 1050624 + 1048576);  // 512 KB

  hipMemsetAsync(counts, 0, 16, stream);
  hipMemsetAsync(perm, 0xFF, (N_ATOMS + 512) * sizeof(int), stream);

  hist_kernel<<<256, 256, 0, stream>>>(sym, counts, N_ATOMS);
  offsets_kernel<<<1, 64, 0, stream>>>(counts, offs, cursors);
  scatter_kernel<<<N_ATOMS / 256, 256, 0, stream>>>(sym, cursors, perm, N_ATOMS);
  wconv_kernel<<<512, 256, 0, stream>>>(W1, W2, wt);
  mlp_gemm<<<2052, 256, 65536, stream>>>(x, wt, perm, offs, b1, b2, W3, b3,
                                         slope, intercept, e_atom);
  segsum_kernel<<<NIMG, 256, 0, stream>>>(e_atom, img, (float*)d_out, N_ATOMS);
}